// Round 2
// baseline (1115.940 us; speedup 1.0000x reference)
//
#include <hip/hip_runtime.h>
#include <stdint.h>

// ---------------------------------------------------------------------------
// NVGPTAttention: qkv(+lora) -> rope -> causal flash attention -> dense
// B=4 S=1024 HID=4096 NH=32 HD=128. fp32 in/out, fp16 MFMA internally.
// R5 = R4 with the GEMM inner loop converted from {12 ds_read, lgkmcnt(0),
// 32 MFMA} to a counted-lgkmcnt interleave: pinned ds_read issue order
// (af0, bf0-3, af1..af7), then lgkmcnt(7)->(0) descent with one 4-MFMA
// row-group after each wait. LDS fragment reads now hide under the MFMA
// cluster instead of bursting while the matrix pipe idles.
// R4 structure kept: 256x256 tile, 8 waves, BK=32, 4-slot LDS ring,
// 3-ahead gll16 prefetch, counted vmcnt (never 0 mid-loop), raw s_barrier,
// setprio around MFMA, source-side XOR chunk swizzle (0 conflicts).
// ---------------------------------------------------------------------------

typedef _Float16 half8 __attribute__((ext_vector_type(8)));
typedef float f32x4 __attribute__((ext_vector_type(4)));

#define B_SZ 4
#define S_SZ 1024
#define HID 4096
#define NH 32
#define HD 128
#define NQKV 12288          // 3*HID
#define M_TOT 4096          // B*S
#define ATT_SCALE 0.08838834764831845f

__device__ __forceinline__ ushort f2h(float x) {
    union { _Float16 h; ushort u; } v; v.h = (_Float16)x; return v.u;
}
__device__ __forceinline__ float h2f(ushort u) {
    union { _Float16 h; ushort u; } v; v.u = u; return (float)v.h;
}

// async global->LDS, 16B per lane. LDS dest is wave-uniform base + lane*16;
// our dest pointers are lane-contiguous so firstlane(base)+lane*16 matches.
__device__ __forceinline__ void gll16(const ushort* g, ushort* l) {
    __builtin_amdgcn_global_load_lds(
        (const __attribute__((address_space(1))) void*)g,
        (__attribute__((address_space(3))) void*)l, 16, 0, 0);
}

// ---------------------------------------------------------------------------
// fp32 -> fp16 cast, 8 elems/thread (weights)
// ---------------------------------------------------------------------------
__global__ __launch_bounds__(256) void cast_f16_kernel(
    const float* __restrict__ src, ushort* __restrict__ dst, int n) {
    int i = (blockIdx.x * 256 + threadIdx.x) * 8;
    if (i >= n) return;
    float4 a = *(const float4*)(src + i);
    float4 b = *(const float4*)(src + i + 4);
    *(ushort4*)(dst + i)     = make_ushort4(f2h(a.x), f2h(a.y), f2h(a.z), f2h(a.w));
    *(ushort4*)(dst + i + 4) = make_ushort4(f2h(b.x), f2h(b.y), f2h(b.z), f2h(b.w));
}

// ---------------------------------------------------------------------------
// lora_mid[b,s,r] = sum_h hidden[b,s,h] * lora_in[b,r,h]   (fp32)
// one block per (b,s) row; 8 threads per r. Also emits hidden as fp16.
// ---------------------------------------------------------------------------
__global__ __launch_bounds__(256) void lora_mid_kernel(
    const float* __restrict__ hidden, const float* __restrict__ lora_in,
    float* __restrict__ lora_mid, ushort* __restrict__ hs_f16) {
    __shared__ float hrow[HID];
    int row = blockIdx.x;            // b*1024+s
    int b = row >> 10;
    int tid = threadIdx.x;
    const float4* h4 = (const float4*)(hidden + (size_t)row * HID);
    for (int i = tid; i < HID / 4; i += 256) ((float4*)hrow)[i] = h4[i];
    __syncthreads();
    // fused fp16 cast of this row
    for (int i = tid; i < 1024; i += 256) {
        float4 v = ((const float4*)hrow)[i];
        *(ushort4*)(hs_f16 + (size_t)row * HID + i * 4) =
            make_ushort4(f2h(v.x), f2h(v.y), f2h(v.z), f2h(v.w));
    }
    int r = tid >> 3, j = tid & 7;
    const float4* lin = (const float4*)(lora_in + ((size_t)b * 32 + r) * HID);
    const float4* hv = (const float4*)hrow;
    float acc = 0.f;
    #pragma unroll 4
    for (int k = 0; k < HID / 32; k++) {
        float4 lv = lin[k * 8 + j];
        float4 hh = hv[k * 8 + j];
        acc += lv.x * hh.x + lv.y * hh.y + lv.z * hh.z + lv.w * hh.w;
    }
    acc += __shfl_xor(acc, 1); acc += __shfl_xor(acc, 2); acc += __shfl_xor(acc, 4);
    if (j == 0) lora_mid[(size_t)row * 32 + r] = acc;
}

// ---------------------------------------------------------------------------
// C[m,n] = sum_k A[m,k]*W[n,k]  (both fp16 row-major along K)
// 256x256 tile, BK=32, 512 thr (8 waves 2x4), mfma_f32_16x16x32_f16.
// Deep pipeline: 4-slot LDS ring, prefetch 3 K-tiles ahead, counted vmcnt.
// Counted-lgkmcnt ds_read/MFMA interleave inside each K-tile (R5).
// LDS rows: 32 elems = 4 x 16B chunks, phys_chunk = chunk ^ ((row>>1)&3),
// applied on the gll16 GLOBAL source (stays in-cacheline) so the lane-linear
// LDS dest constraint holds; frag reads XOR the same -> conflict-free b128.
// LORA: C += lora_mid[m,:32] . lora_out[b, n, :32] as one rank-32 MFMA pass.
// ---------------------------------------------------------------------------
#define SB() __builtin_amdgcn_sched_barrier(0)

template <int OUT_F16, int LORA>
__global__ __launch_bounds__(512, 2) void gemm_bt_kernel(
    const ushort* __restrict__ A, const ushort* __restrict__ W,
    void* __restrict__ Cout, int M, int N, int K,
    const float* __restrict__ lora_mid, const float* __restrict__ lora_out) {
    // ring[4] x {A,B} x 256rows x 32elems fp16 = 128 KiB
    __shared__ __attribute__((aligned(16))) ushort lds[4][2][256 * 32];
    const int tid = threadIdx.x;          // 0..511
    const int lane = tid & 63;
    const int wave = tid >> 6;            // 0..7
    const int bm = blockIdx.y, bn = blockIdx.x;
    const int wm = wave >> 2, wn = wave & 3;     // 2 x 4 wave grid
    const int l15 = lane & 15, quad = lane >> 4;
    const int swz = (l15 >> 1) & 3;              // read-side XOR
    const int srow = tid >> 2;                   // staging row (0..127)
    const int csrc = (tid & 3) ^ ((srow >> 1) & 3);   // swizzled source chunk
    const ushort* Ag = A + (size_t)(bm * 256 + srow) * K + csrc * 8;
    const ushort* Wg = W + (size_t)(bn * 256 + srow) * K + csrc * 8;
    const size_t hstep = (size_t)128 * K;        // rows 128..255 of the tile

    f32x4 acc[8][4];
    #pragma unroll
    for (int mi = 0; mi < 8; mi++)
        #pragma unroll
        for (int ni = 0; ni < 4; ni++) acc[mi][ni] = (f32x4){0.f, 0.f, 0.f, 0.f};

    const int nT = K >> 5;                // K-tiles of 32 (128 here)

    // stage K-tile t into ring slot t&3: 4 gll16 per thread (=4 vmcnt ticks)
    auto STAGE = [&](int t_) {
        ushort* dA = &lds[t_ & 3][0][0] + tid * 8;
        ushort* dB = &lds[t_ & 3][1][0] + tid * 8;
        const int kk = t_ << 5;
        gll16(Ag + kk, dA);
        gll16(Ag + hstep + kk, dA + 128 * 32);
        gll16(Wg + kk, dB);
        gll16(Wg + hstep + kk, dB + 128 * 32);
    };

    STAGE(0); STAGE(1); STAGE(2);                 // 12 loads in flight
    asm volatile("s_waitcnt vmcnt(8)" ::: "memory");   // tile 0 complete
    __builtin_amdgcn_s_barrier();
    SB();

#define LDA(mi) af[mi] = *(const half8*)(Ab + (wm * 128 + (mi) * 16 + l15) * 32 + (quad ^ swz) * 8)
#define LDB(ni) bf[ni] = *(const half8*)(Bb + (wn * 64 + (ni) * 16 + l15) * 32 + (quad ^ swz) * 8)
#define MROW(mi) do { \
    acc[mi][0] = __builtin_amdgcn_mfma_f32_16x16x32_f16(af[mi], bf[0], acc[mi][0], 0, 0, 0); \
    acc[mi][1] = __builtin_amdgcn_mfma_f32_16x16x32_f16(af[mi], bf[1], acc[mi][1], 0, 0, 0); \
    acc[mi][2] = __builtin_amdgcn_mfma_f32_16x16x32_f16(af[mi], bf[2], acc[mi][2], 0, 0, 0); \
    acc[mi][3] = __builtin_amdgcn_mfma_f32_16x16x32_f16(af[mi], bf[3], acc[mi][3], 0, 0, 0); } while (0)
#define WAITL(n) asm volatile("s_waitcnt lgkmcnt(" #n ")" ::: "memory")

    for (int t = 0; t < nT; ++t) {
        const ushort* Ab = &lds[t & 3][0][0];
        const ushort* Bb = &lds[t & 3][1][0];
        if (t + 3 < nT) STAGE(t + 3);     // prefetch into slot consumed at t-1
        half8 af[8], bf[4];
        // pinned issue order: af0, bf0-3, af1..af7 (12 ds_read_b128).
        // DS returns in-order per wave -> counted lgkm waits map exactly.
        LDA(0); SB(); LDB(0); SB(); LDB(1); SB(); LDB(2); SB(); LDB(3); SB();
        LDA(1); SB(); LDA(2); SB(); LDA(3); SB(); LDA(4); SB();
        LDA(5); SB(); LDA(6); SB(); LDA(7); SB();
        __builtin_amdgcn_s_setprio(1);
        WAITL(7); SB(); MROW(0); SB();    // af0,bf0-3 landed
        WAITL(6); SB(); MROW(1); SB();    // +af1
        WAITL(5); SB(); MROW(2); SB();
        WAITL(4); SB(); MROW(3); SB();
        WAITL(3); SB(); MROW(4); SB();
        WAITL(2); SB(); MROW(5); SB();
        WAITL(1); SB(); MROW(6); SB();
        WAITL(0); SB(); MROW(7); SB();
        __builtin_amdgcn_s_setprio(0);
        // counted wait: keep 2 tiles (8 loads) in flight across the barrier.
        if (t + 3 < nT)      asm volatile("s_waitcnt vmcnt(8)" ::: "memory");
        else if (t + 2 < nT) asm volatile("s_waitcnt vmcnt(4)" ::: "memory");
        else                 asm volatile("s_waitcnt vmcnt(0)" ::: "memory");
        __builtin_amdgcn_s_barrier();
        SB();
    }
#undef LDA
#undef LDB
#undef MROW
#undef WAITL

    if (LORA) {
        // all staging drained (vmcnt(0) on last iters) and all reads done
        // (lgkmcnt(0) before final barrier) -> safe to overwrite slot 0.
        const float4* lmg = (const float4*)(lora_mid + (size_t)bm * 256 * 32);
        const int bb = (bm * 256) >> 10;     // tile is within one batch
        const float4* log_ = (const float4*)(lora_out + ((size_t)bb * N + (size_t)bn * 256) * 32);
        ushort* As = &lds[0][0][0];
        ushort* Bs = &lds[0][1][0];
        for (int i = tid; i < 2048; i += 512) {
            int row = i >> 3, hf = i & 1, clog = (i >> 1) & 3;
            int phys = clog ^ ((row >> 1) & 3);
            int off = row * 32 + phys * 8 + hf * 4;
            float4 v = lmg[i];
            *(ushort4*)(As + off) = make_ushort4(f2h(v.x), f2h(v.y), f2h(v.z), f2h(v.w));
            float4 w2 = log_[i];
            *(ushort4*)(Bs + off) = make_ushort4(f2h(w2.x), f2h(w2.y), f2h(w2.z), f2h(w2.w));
        }
        __syncthreads();
        half8 af[8], bf[4];
        #pragma unroll
        for (int mi = 0; mi < 8; mi++)
            af[mi] = *(const half8*)(As + (wm * 128 + mi * 16 + l15) * 32 + (quad ^ swz) * 8);
        #pragma unroll
        for (int ni = 0; ni < 4; ni++)
            bf[ni] = *(const half8*)(Bs + (wn * 64 + ni * 16 + l15) * 32 + (quad ^ swz) * 8);
        #pragma unroll
        for (int mi = 0; mi < 8; mi++)
            #pragma unroll
            for (int ni = 0; ni < 4; ni++)
                acc[mi][ni] = __builtin_amdgcn_mfma_f32_16x16x32_f16(
                    af[mi], bf[ni], acc[mi][ni], 0, 0, 0);
    }

    // Epilogue. C/D layout: row = quad*4 + r, col = l15  (m89-verified).
    #pragma unroll
    for (int mi = 0; mi < 8; mi++) {
        int row0 = bm * 256 + wm * 128 + mi * 16 + quad * 4;
        #pragma unroll
        for (int ni = 0; ni < 4; ni++) {
            int col = bn * 256 + wn * 64 + ni * 16 + l15;
            #pragma unroll
            for (int r = 0; r < 4; r++) {
                size_t idx = (size_t)(row0 + r) * N + col;
                if (OUT_F16) ((ushort*)Cout)[idx] = f2h(acc[mi][ni][r]);
                else         ((float*)Cout)[idx] = acc[mi][ni][r];
            }
        }
    }
}

// ---------------------------------------------------------------------------
// RoPE on q,k + transpose (B,S,NH,HD) -> (B,NH,S,HD). ATT_SCALE folded into q.
// ---------------------------------------------------------------------------
__global__ __launch_bounds__(256) void rope_kernel(
    const int* __restrict__ positions, const ushort* __restrict__ qkv,
    ushort* __restrict__ q_t, ushort* __restrict__ k_t) {
    int id = blockIdx.x * 256 + threadIdx.x;     // < B*S*NH*64
    int j = id & 63;
    int h = (id >> 6) & 31;
    int s = (id >> 11) & 1023;
    int b = id >> 21;
    float pos = (float)positions[s];
    float f = pos * __expf(-0.1439115683121279f * (float)j);
    float c = __cosf(f), sn = __sinf(f);
    size_t base_in = ((size_t)((b << 10) + s)) * NQKV + h * 128 + j;
    float q1 = h2f(qkv[base_in]),        q2 = h2f(qkv[base_in + 64]);
    float k1 = h2f(qkv[base_in + 4096]), k2 = h2f(qkv[base_in + 4160]);
    size_t dst = (((size_t)((b << 5) + h) << 10) + s) * 128 + j;
    q_t[dst]      = f2h((q1 * c - q2 * sn) * ATT_SCALE);
    q_t[dst + 64] = f2h((q2 * c + q1 * sn) * ATT_SCALE);
    k_t[dst]      = f2h(k1 * c - k2 * sn);
    k_t[dst + 64] = f2h(k2 * c + k1 * sn);
}

// ---------------------------------------------------------------------------
// v transpose: qkv v-part (B,S,NH,HD) -> v_t (B,NH,HD,S), LDS-tiled 64x128
// ---------------------------------------------------------------------------
__global__ __launch_bounds__(256) void transpose_v_kernel(
    const ushort* __restrict__ qkv, ushort* __restrict__ v_t) {
    __shared__ __attribute__((aligned(16))) ushort tile[64][132];  // +4 pad
    int st = blockIdx.x, bh = blockIdx.y;
    int b = bh >> 5, h = bh & 31;
    int tid = threadIdx.x;
    #pragma unroll
    for (int i = 0; i < 8; i++) {
        int idx = i * 256 + tid;         // 2048 x ushort4
        int r = idx >> 5, c = idx & 31;
        ushort4 v = *(const ushort4*)(qkv +
            (size_t)((b << 10) + st * 64 + r) * NQKV + 8192 + h * 128 + c * 4);
        *(ushort4*)(&tile[r][c * 4]) = v;
    }
    __syncthreads();
    int sp = tid & 63, dg = tid >> 6;
    #pragma unroll
    for (int i = 0; i < 32; i++) {
        int d = i * 4 + dg;
        v_t[(size_t)(bh * 128 + d) * 1024 + st * 64 + sp] = tile[sp][d];
    }
}

// ---------------------------------------------------------------------------
// Flash attention, causal. One block (256 thr, 4 waves) per (qtile=64, b*h).
// K/V tiles of 64. gll16-staged Q/K/V with source-side XOR swizzle
// (phys_chunk = chunk ^ (row&7), 16B chunks) -> 2-way-max bank aliasing.
// Fixed-reference softmax: p = exp(s-4); l reduced once after the loop.
// P round-trip through wave-private LDS (no barrier; lgkmcnt wait only).
// LDS 56KB -> 2 blocks/CU.
// ---------------------------------------------------------------------------
__global__ __launch_bounds__(256) void flash_kernel(
    const ushort* __restrict__ q_t, const ushort* __restrict__ k_t,
    const ushort* __restrict__ v_t, ushort* __restrict__ attn) {
    __shared__ __attribute__((aligned(16))) ushort Qs[64 * 128];
    __shared__ __attribute__((aligned(16))) ushort Ks[64 * 128];
    __shared__ __attribute__((aligned(16))) ushort Vs[128 * 64];   // (d, s)
    __shared__ __attribute__((aligned(16))) ushort Ps[4 * 16 * 64];
    const int qtile = blockIdx.x, bh = blockIdx.y;
    const int b = bh >> 5, h = bh & 31;
    const int tid = threadIdx.x, lane = tid & 63, w = tid >> 6;
    const int l15 = lane & 15, quad = lane >> 4;
    const int swz = l15 & 7;

    const ushort* qg = q_t + ((size_t)bh * 1024 + qtile * 64) * 128;
    #pragma unroll
    for (int i = 0; i < 4; i++) {
        int idx = i * 256 + tid, row = idx >> 4, cp = idx & 15;
        gll16(qg + row * 128 + (cp ^ (row & 7)) * 8, Qs + idx * 8);
    }

    f32x4 O[8];
    #pragma unroll
    for (int dt = 0; dt < 8; dt++) O[dt] = (f32x4){0.f, 0.f, 0.f, 0.f};
    float l_part[4] = {0.f, 0.f, 0.f, 0.f};
    __syncthreads();                           // Q staged (drains vmcnt)

    for (int kt = 0; kt <= qtile; kt++) {
        if (kt) __syncthreads();               // prior QK/PV reads done
        const ushort* kg = k_t + ((size_t)bh * 1024 + kt * 64) * 128;
        #pragma unroll
        for (int i = 0; i < 4; i++) {
            int idx = i * 256 + tid, row = idx >> 4, cp = idx & 15;
            gll16(kg + row * 128 + (cp ^ (row & 7)) * 8, Ks + idx * 8);
        }
        const ushort* vg = v_t + (size_t)bh * 128 * 1024 + kt * 64;
        #pragma unroll
        for (int i = 0; i < 4; i++) {
            int idx = i * 256 + tid, d = idx >> 3, cp = idx & 7;
            gll16(vg + (size_t)d * 1024 + (cp ^ (d & 7)) * 8, Vs + idx * 8);
        }
        __syncthreads();                       // staging visible

        // S = Q K^T  (scale pre-folded into Q)
        f32x4 sa[4];
        #pragma unroll
        for (int nt = 0; nt < 4; nt++) sa[nt] = (f32x4){0.f, 0.f, 0.f, 0.f};
        #pragma unroll
        for (int c = 0; c < 4; c++) {
            half8 a = *(const half8*)(Qs + (w * 16 + l15) * 128 + ((c * 4 + quad) ^ swz) * 8);
            #pragma unroll
            for (int nt = 0; nt < 4; nt++) {
                half8 kb = *(const half8*)(Ks + (nt * 16 + l15) * 128 + ((c * 4 + quad) ^ swz) * 8);
                sa[nt] = __builtin_amdgcn_mfma_f32_16x16x32_f16(a, kb, sa[nt], 0, 0, 0);
            }
        }

        // fixed-ref softmax: p = exp(s - 4); accumulate per-lane row sums
        const int rowg = qtile * 64 + w * 16 + quad * 4;
        const bool diag = (kt == qtile);
        #pragma unroll
        for (int nt = 0; nt < 4; nt++) {
            int colg = kt * 64 + nt * 16 + l15;
            #pragma unroll
            for (int r = 0; r < 4; r++) {
                float s = sa[nt][r];
                if (diag && colg > rowg + r) s = -1e30f;
                float p = __expf(s - 4.0f);
                l_part[r] += p;
                int prow = quad * 4 + r;
                int clog = nt * 2 + (l15 >> 3);
                Ps[w * 1024 + prow * 64 + (clog ^ (prow & 7)) * 8 + (l15 & 7)] = f2h(p);
            }
        }
        // Ps is wave-private: DS ops per-wave are in-order; stop compiler
        // reordering + wait for the writes, no s_barrier needed.
        asm volatile("s_waitcnt lgkmcnt(0)" ::: "memory");

        // O += P V   (P in A-layout via swizzled LDS; V rows = output dim d)
        half8 pa[2];
        #pragma unroll
        for (int c2 = 0; c2 < 2; c2++)
            pa[c2] = *(const half8*)(Ps + w * 1024 + l15 * 64 + ((c2 * 4 + quad) ^ swz) * 8);
        #pragma unroll
        for (int dt = 0; dt < 8; dt++)
            #pragma unroll
            for (int c2 = 0; c2 < 2; c2++) {
                half8 vb = *(const half8*)(Vs + (dt * 16 + l15) * 64 + ((c2 * 4 + quad) ^ swz) * 8);
                O[dt] = __builtin_amdgcn_mfma_f32_16x16x32_f16(pa[c2], vb, O[dt], 0, 0, 0);
            }
    }

    // reduce l across the 16 lanes sharing each row group, normalize, store
    #pragma unroll
    for (int r = 0; r < 4; r++) {
        float l = l_part[r];
        l += __shfl_xor(l, 1); l += __shfl_xor(l, 2);
        l += __shfl_xor(l, 4); l += __shfl_xor(l, 8);
        l_part[r] = 1.f / l;
    }
    #pragma unroll
    for (int dt = 0; dt < 8; dt++)
        #pragma unroll
        for (int r = 0; r < 4; r++) {
            int srow = qtile * 64 + w * 16 + quad * 4 + r;
            attn[(size_t)((b << 10) + srow) * HID + h * 128 + dt * 16 + l15] =
                f2h(O[dt][r] * l_part[r]);
        }
}

// ---------------------------------------------------------------------------
extern "C" void kernel_launch(void* const* d_in, const int* in_sizes, int n_in,
                              void* d_out, int out_size, void* d_ws, size_t ws_size,
                              hipStream_t stream) {
    const int*   positions = (const int*)d_in[0];
    const float* hidden    = (const float*)d_in[1];
    const float* w_qkv     = (const float*)d_in[2];
    const float* w_dense   = (const float*)d_in[3];
    const float* lora_in   = (const float*)d_in[4];
    const float* lora_out  = (const float*)d_in[5];
    float* out = (float*)d_out;
    char* ws = (char*)d_ws;

    // workspace layout (regions reused over the timeline)
    ushort* hs_f16   = (ushort*)(ws + 0);            // 32 MiB
    ushort* wqkv_f16 = (ushort*)(ws + 33554432);     // 96 MiB
    float*  lmid     = (float*) (ws + 134217728);    // 512 KiB
    ushort* qkv_f16  = (ushort*)(ws + 134742016);    // 96 MiB
    ushort* q_t      = (ushort*)(ws + 0);            // reuse hs region
    ushort* k_t      = (ushort*)(ws + 33554432);     // reuse wqkv region
    ushort* v_t      = (ushort*)(ws + 67108864);
    ushort* wd_f16   = (ushort*)(ws + 134742016);    // reuse qkv region (cast AFTER transpose_v!)
    ushort* attn_f16 = (ushort*)(ws + 168296448);

    cast_f16_kernel<<<24576, 256, 0, stream>>>(w_qkv, wqkv_f16, NQKV * HID);
    lora_mid_kernel<<<M_TOT, 256, 0, stream>>>(hidden, lora_in, lmid, hs_f16);
    gemm_bt_kernel<1, 1><<<dim3(NQKV / 256, M_TOT / 256), 512, 0, stream>>>(
        hs_f16, wqkv_f16, qkv_f16, M_TOT, NQKV, HID, lmid, lora_out);
    rope_kernel<<<32768, 256, 0, stream>>>(positions, qkv_f16, q_t, k_t);
    transpose_v_kernel<<<dim3(16, 128), 256, 0, stream>>>(qkv_f16, v_t);
    // wd_f16 aliases qkv_f16: this cast must come after the last qkv reader.
    cast_f16_kernel<<<8192, 256, 0, stream>>>(w_dense, wd_f16, HID * HID);
    flash_kernel<<<dim3(16, 128), 256, 0, stream>>>(q_t, k_t, v_t, attn_f16);
    gemm_bt_kernel<0, 0><<<dim3(HID / 256, M_TOT / 256), 512, 0, stream>>>(
        attn_f16, wd_f16, out, M_TOT, HID, HID, nullptr, nullptr);
}

// Round 3
// 1097.025 us; speedup vs baseline: 1.0172x; 1.0172x over previous
//
#include <hip/hip_runtime.h>
#include <stdint.h>

// ---------------------------------------------------------------------------
// NVGPTAttention: qkv(+lora) -> rope -> causal flash attention -> dense
// B=4 S=1024 HID=4096 NH=32 HD=128. fp32 in/out, fp16 MFMA internally.
// R6 = R4 (R5's manual lgkmcnt descent REVERTED - it regressed 375->395) plus:
//   1. T1 bijective XCD swizzle on both GEMMs and flash: each XCD gets a
//      bm-contiguous chunk -> A-panel (4MB) L2-resident, B via L3.
//   2. 2-sub-phase GEMM tile body: {af0-3,bf} 16 MFMA | sched_barrier(0) |
//      {af4-7} 16 MFMA. Compile-time fence only (no runtime barrier):
//      halves the per-wave DS burst, staggers LDS queue vs MFMA.
// R4 structure kept: 256x256 tile, 8 waves, BK=32, 4-slot LDS ring,
// 3-ahead gll16 prefetch, counted vmcnt (never 0 mid-loop), raw s_barrier,
// setprio around MFMA, source-side XOR chunk swizzle (0 conflicts).
// ---------------------------------------------------------------------------

typedef _Float16 half8 __attribute__((ext_vector_type(8)));
typedef float f32x4 __attribute__((ext_vector_type(4)));

#define B_SZ 4
#define S_SZ 1024
#define HID 4096
#define NH 32
#define HD 128
#define NQKV 12288          // 3*HID
#define M_TOT 4096          // B*S
#define ATT_SCALE 0.08838834764831845f

__device__ __forceinline__ ushort f2h(float x) {
    union { _Float16 h; ushort u; } v; v.h = (_Float16)x; return v.u;
}
__device__ __forceinline__ float h2f(ushort u) {
    union { _Float16 h; ushort u; } v; v.u = u; return (float)v.h;
}

// async global->LDS, 16B per lane. LDS dest is wave-uniform base + lane*16;
// our dest pointers are lane-contiguous so firstlane(base)+lane*16 matches.
__device__ __forceinline__ void gll16(const ushort* g, ushort* l) {
    __builtin_amdgcn_global_load_lds(
        (const __attribute__((address_space(1))) void*)g,
        (__attribute__((address_space(3))) void*)l, 16, 0, 0);
}

#define SB() __builtin_amdgcn_sched_barrier(0)

// ---------------------------------------------------------------------------
// fp32 -> fp16 cast, 8 elems/thread (weights)
// ---------------------------------------------------------------------------
__global__ __launch_bounds__(256) void cast_f16_kernel(
    const float* __restrict__ src, ushort* __restrict__ dst, int n) {
    int i = (blockIdx.x * 256 + threadIdx.x) * 8;
    if (i >= n) return;
    float4 a = *(const float4*)(src + i);
    float4 b = *(const float4*)(src + i + 4);
    *(ushort4*)(dst + i)     = make_ushort4(f2h(a.x), f2h(a.y), f2h(a.z), f2h(a.w));
    *(ushort4*)(dst + i + 4) = make_ushort4(f2h(b.x), f2h(b.y), f2h(b.z), f2h(b.w));
}

// ---------------------------------------------------------------------------
// lora_mid[b,s,r] = sum_h hidden[b,s,h] * lora_in[b,r,h]   (fp32)
// one block per (b,s) row; 8 threads per r. Also emits hidden as fp16.
// ---------------------------------------------------------------------------
__global__ __launch_bounds__(256) void lora_mid_kernel(
    const float* __restrict__ hidden, const float* __restrict__ lora_in,
    float* __restrict__ lora_mid, ushort* __restrict__ hs_f16) {
    __shared__ float hrow[HID];
    int row = blockIdx.x;            // b*1024+s
    int b = row >> 10;
    int tid = threadIdx.x;
    const float4* h4 = (const float4*)(hidden + (size_t)row * HID);
    for (int i = tid; i < HID / 4; i += 256) ((float4*)hrow)[i] = h4[i];
    __syncthreads();
    // fused fp16 cast of this row
    for (int i = tid; i < 1024; i += 256) {
        float4 v = ((const float4*)hrow)[i];
        *(ushort4*)(hs_f16 + (size_t)row * HID + i * 4) =
            make_ushort4(f2h(v.x), f2h(v.y), f2h(v.z), f2h(v.w));
    }
    int r = tid >> 3, j = tid & 7;
    const float4* lin = (const float4*)(lora_in + ((size_t)b * 32 + r) * HID);
    const float4* hv = (const float4*)hrow;
    float acc = 0.f;
    #pragma unroll 4
    for (int k = 0; k < HID / 32; k++) {
        float4 lv = lin[k * 8 + j];
        float4 hh = hv[k * 8 + j];
        acc += lv.x * hh.x + lv.y * hh.y + lv.z * hh.z + lv.w * hh.w;
    }
    acc += __shfl_xor(acc, 1); acc += __shfl_xor(acc, 2); acc += __shfl_xor(acc, 4);
    if (j == 0) lora_mid[(size_t)row * 32 + r] = acc;
}

// ---------------------------------------------------------------------------
// C[m,n] = sum_k A[m,k]*W[n,k]  (both fp16 row-major along K)
// 256x256 tile, BK=32, 512 thr (8 waves 2x4), mfma_f32_16x16x32_f16.
// Deep pipeline: 4-slot LDS ring, prefetch 3 K-tiles ahead, counted vmcnt.
// XCD-swizzled block mapping: each XCD owns a bm-contiguous chunk.
// LDS rows: 32 elems = 4 x 16B chunks, phys_chunk = chunk ^ ((row>>1)&3),
// applied on the gll16 GLOBAL source (stays in-cacheline) so the lane-linear
// LDS dest constraint holds; frag reads XOR the same -> conflict-free b128.
// LORA: C += lora_mid[m,:32] . lora_out[b, n, :32] as one rank-32 MFMA pass.
// ---------------------------------------------------------------------------
template <int OUT_F16, int LORA>
__global__ __launch_bounds__(512, 2) void gemm_bt_kernel(
    const ushort* __restrict__ A, const ushort* __restrict__ W,
    void* __restrict__ Cout, int M, int N, int K,
    const float* __restrict__ lora_mid, const float* __restrict__ lora_out) {
    // ring[4] x {A,B} x 256rows x 32elems fp16 = 128 KiB
    __shared__ __attribute__((aligned(16))) ushort lds[4][2][256 * 32];
    const int tid = threadIdx.x;          // 0..511
    const int lane = tid & 63;
    const int wave = tid >> 6;            // 0..7
    // T1: bijective XCD chunk swizzle (nwg % 8 == 0 for both grids: 768, 256)
    const int gx = gridDim.x;
    int lid = blockIdx.y * gx + blockIdx.x;
    const int cpx = (gx * gridDim.y) >> 3;
    lid = (lid & 7) * cpx + (lid >> 3);
    const int bm = lid / gx, bn = lid - bm * gx;
    const int wm = wave >> 2, wn = wave & 3;     // 2 x 4 wave grid
    const int l15 = lane & 15, quad = lane >> 4;
    const int swz = (l15 >> 1) & 3;              // read-side XOR
    const int srow = tid >> 2;                   // staging row (0..127)
    const int csrc = (tid & 3) ^ ((srow >> 1) & 3);   // swizzled source chunk
    const ushort* Ag = A + (size_t)(bm * 256 + srow) * K + csrc * 8;
    const ushort* Wg = W + (size_t)(bn * 256 + srow) * K + csrc * 8;
    const size_t hstep = (size_t)128 * K;        // rows 128..255 of the tile

    f32x4 acc[8][4];
    #pragma unroll
    for (int mi = 0; mi < 8; mi++)
        #pragma unroll
        for (int ni = 0; ni < 4; ni++) acc[mi][ni] = (f32x4){0.f, 0.f, 0.f, 0.f};

    const int nT = K >> 5;                // K-tiles of 32 (128 here)

    // stage K-tile t into ring slot t&3: 4 gll16 per thread (=4 vmcnt ticks)
    auto STAGE = [&](int t_) {
        ushort* dA = &lds[t_ & 3][0][0] + tid * 8;
        ushort* dB = &lds[t_ & 3][1][0] + tid * 8;
        const int kk = t_ << 5;
        gll16(Ag + kk, dA);
        gll16(Ag + hstep + kk, dA + 128 * 32);
        gll16(Wg + kk, dB);
        gll16(Wg + hstep + kk, dB + 128 * 32);
    };

    STAGE(0); STAGE(1); STAGE(2);                 // 12 loads in flight
    asm volatile("s_waitcnt vmcnt(8)" ::: "memory");   // tile 0 complete
    __builtin_amdgcn_s_barrier();
    SB();

    for (int t = 0; t < nT; ++t) {
        const ushort* Ab = &lds[t & 3][0][0];
        const ushort* Bb = &lds[t & 3][1][0];
        if (t + 3 < nT) STAGE(t + 3);     // prefetch into slot consumed at t-1
        // ---- sub-phase A: rows 0-63 of the wave tile ----
        half8 af[4], bf[4];
        #pragma unroll
        for (int mi = 0; mi < 4; mi++)
            af[mi] = *(const half8*)(Ab + (wm * 128 + mi * 16 + l15) * 32 + (quad ^ swz) * 8);
        #pragma unroll
        for (int ni = 0; ni < 4; ni++)
            bf[ni] = *(const half8*)(Bb + (wn * 64 + ni * 16 + l15) * 32 + (quad ^ swz) * 8);
        __builtin_amdgcn_s_setprio(1);
        #pragma unroll
        for (int mi = 0; mi < 4; mi++)
            #pragma unroll
            for (int ni = 0; ni < 4; ni++)
                acc[mi][ni] = __builtin_amdgcn_mfma_f32_16x16x32_f16(
                    af[mi], bf[ni], acc[mi][ni], 0, 0, 0);
        __builtin_amdgcn_s_setprio(0);
        SB();   // compile-time phase split only (no runtime barrier)
        // ---- sub-phase B: rows 64-127 of the wave tile ----
        half8 ag[4];
        #pragma unroll
        for (int mi = 0; mi < 4; mi++)
            ag[mi] = *(const half8*)(Ab + (wm * 128 + (mi + 4) * 16 + l15) * 32 + (quad ^ swz) * 8);
        __builtin_amdgcn_s_setprio(1);
        #pragma unroll
        for (int mi = 0; mi < 4; mi++)
            #pragma unroll
            for (int ni = 0; ni < 4; ni++)
                acc[mi + 4][ni] = __builtin_amdgcn_mfma_f32_16x16x32_f16(
                    ag[mi], bf[ni], acc[mi + 4][ni], 0, 0, 0);
        __builtin_amdgcn_s_setprio(0);
        // counted wait: keep 2 tiles (8 loads) in flight across the barrier.
        if (t + 3 < nT)      asm volatile("s_waitcnt vmcnt(8)" ::: "memory");
        else if (t + 2 < nT) asm volatile("s_waitcnt vmcnt(4)" ::: "memory");
        else                 asm volatile("s_waitcnt vmcnt(0)" ::: "memory");
        __builtin_amdgcn_s_barrier();
        SB();
    }

    if (LORA) {
        // all staging drained (vmcnt(0) on last iters) and all reads done
        // (reads precede each wave's MFMAs which precede the final barrier)
        // -> safe to overwrite slot 0.
        const float4* lmg = (const float4*)(lora_mid + (size_t)bm * 256 * 32);
        const int bb = (bm * 256) >> 10;     // tile is within one batch
        const float4* log_ = (const float4*)(lora_out + ((size_t)bb * N + (size_t)bn * 256) * 32);
        ushort* As = &lds[0][0][0];
        ushort* Bs = &lds[0][1][0];
        for (int i = tid; i < 2048; i += 512) {
            int row = i >> 3, hf = i & 1, clog = (i >> 1) & 3;
            int phys = clog ^ ((row >> 1) & 3);
            int off = row * 32 + phys * 8 + hf * 4;
            float4 v = lmg[i];
            *(ushort4*)(As + off) = make_ushort4(f2h(v.x), f2h(v.y), f2h(v.z), f2h(v.w));
            float4 w2 = log_[i];
            *(ushort4*)(Bs + off) = make_ushort4(f2h(w2.x), f2h(w2.y), f2h(w2.z), f2h(w2.w));
        }
        __syncthreads();
        half8 af[8], bf[4];
        #pragma unroll
        for (int mi = 0; mi < 8; mi++)
            af[mi] = *(const half8*)(As + (wm * 128 + mi * 16 + l15) * 32 + (quad ^ swz) * 8);
        #pragma unroll
        for (int ni = 0; ni < 4; ni++)
            bf[ni] = *(const half8*)(Bs + (wn * 64 + ni * 16 + l15) * 32 + (quad ^ swz) * 8);
        #pragma unroll
        for (int mi = 0; mi < 8; mi++)
            #pragma unroll
            for (int ni = 0; ni < 4; ni++)
                acc[mi][ni] = __builtin_amdgcn_mfma_f32_16x16x32_f16(
                    af[mi], bf[ni], acc[mi][ni], 0, 0, 0);
    }

    // Epilogue. C/D layout: row = quad*4 + r, col = l15  (m89-verified).
    #pragma unroll
    for (int mi = 0; mi < 8; mi++) {
        int row0 = bm * 256 + wm * 128 + mi * 16 + quad * 4;
        #pragma unroll
        for (int ni = 0; ni < 4; ni++) {
            int col = bn * 256 + wn * 64 + ni * 16 + l15;
            #pragma unroll
            for (int r = 0; r < 4; r++) {
                size_t idx = (size_t)(row0 + r) * N + col;
                if (OUT_F16) ((ushort*)Cout)[idx] = f2h(acc[mi][ni][r]);
                else         ((float*)Cout)[idx] = acc[mi][ni][r];
            }
        }
    }
}

// ---------------------------------------------------------------------------
// RoPE on q,k + transpose (B,S,NH,HD) -> (B,NH,S,HD). ATT_SCALE folded into q.
// ---------------------------------------------------------------------------
__global__ __launch_bounds__(256) void rope_kernel(
    const int* __restrict__ positions, const ushort* __restrict__ qkv,
    ushort* __restrict__ q_t, ushort* __restrict__ k_t) {
    int id = blockIdx.x * 256 + threadIdx.x;     // < B*S*NH*64
    int j = id & 63;
    int h = (id >> 6) & 31;
    int s = (id >> 11) & 1023;
    int b = id >> 21;
    float pos = (float)positions[s];
    float f = pos * __expf(-0.1439115683121279f * (float)j);
    float c = __cosf(f), sn = __sinf(f);
    size_t base_in = ((size_t)((b << 10) + s)) * NQKV + h * 128 + j;
    float q1 = h2f(qkv[base_in]),        q2 = h2f(qkv[base_in + 64]);
    float k1 = h2f(qkv[base_in + 4096]), k2 = h2f(qkv[base_in + 4160]);
    size_t dst = (((size_t)((b << 5) + h) << 10) + s) * 128 + j;
    q_t[dst]      = f2h((q1 * c - q2 * sn) * ATT_SCALE);
    q_t[dst + 64] = f2h((q2 * c + q1 * sn) * ATT_SCALE);
    k_t[dst]      = f2h(k1 * c - k2 * sn);
    k_t[dst + 64] = f2h(k2 * c + k1 * sn);
}

// ---------------------------------------------------------------------------
// v transpose: qkv v-part (B,S,NH,HD) -> v_t (B,NH,HD,S), LDS-tiled 64x128
// ---------------------------------------------------------------------------
__global__ __launch_bounds__(256) void transpose_v_kernel(
    const ushort* __restrict__ qkv, ushort* __restrict__ v_t) {
    __shared__ __attribute__((aligned(16))) ushort tile[64][132];  // +4 pad
    int st = blockIdx.x, bh = blockIdx.y;
    int b = bh >> 5, h = bh & 31;
    int tid = threadIdx.x;
    #pragma unroll
    for (int i = 0; i < 8; i++) {
        int idx = i * 256 + tid;         // 2048 x ushort4
        int r = idx >> 5, c = idx & 31;
        ushort4 v = *(const ushort4*)(qkv +
            (size_t)((b << 10) + st * 64 + r) * NQKV + 8192 + h * 128 + c * 4);
        *(ushort4*)(&tile[r][c * 4]) = v;
    }
    __syncthreads();
    int sp = tid & 63, dg = tid >> 6;
    #pragma unroll
    for (int i = 0; i < 32; i++) {
        int d = i * 4 + dg;
        v_t[(size_t)(bh * 128 + d) * 1024 + st * 64 + sp] = tile[sp][d];
    }
}

// ---------------------------------------------------------------------------
// Flash attention, causal. One block (256 thr, 4 waves) per (qtile=64, b*h).
// K/V tiles of 64. gll16-staged Q/K/V with source-side XOR swizzle
// (phys_chunk = chunk ^ (row&7), 16B chunks) -> 2-way-max bank aliasing.
// Fixed-reference softmax: p = exp(s-4); l reduced once after the loop.
// P round-trip through wave-private LDS (no barrier; lgkmcnt wait only).
// LDS 56KB -> 2 blocks/CU. XCD-swizzled so 16 consecutive bh share an XCD
// (K/V L2 locality).
// ---------------------------------------------------------------------------
__global__ __launch_bounds__(256) void flash_kernel(
    const ushort* __restrict__ q_t, const ushort* __restrict__ k_t,
    const ushort* __restrict__ v_t, ushort* __restrict__ attn) {
    __shared__ __attribute__((aligned(16))) ushort Qs[64 * 128];
    __shared__ __attribute__((aligned(16))) ushort Ks[64 * 128];
    __shared__ __attribute__((aligned(16))) ushort Vs[128 * 64];   // (d, s)
    __shared__ __attribute__((aligned(16))) ushort Ps[4 * 16 * 64];
    // T1: 2048 wgs -> 256 per XCD = 16 bh x all 16 qtiles
    int lid = blockIdx.y * 16 + blockIdx.x;
    lid = (lid & 7) * 256 + (lid >> 3);
    const int qtile = lid & 15, bh = lid >> 4;
    const int b = bh >> 5, h = bh & 31;
    const int tid = threadIdx.x, lane = tid & 63, w = tid >> 6;
    const int l15 = lane & 15, quad = lane >> 4;
    const int swz = l15 & 7;

    const ushort* qg = q_t + ((size_t)bh * 1024 + qtile * 64) * 128;
    #pragma unroll
    for (int i = 0; i < 4; i++) {
        int idx = i * 256 + tid, row = idx >> 4, cp = idx & 15;
        gll16(qg + row * 128 + (cp ^ (row & 7)) * 8, Qs + idx * 8);
    }

    f32x4 O[8];
    #pragma unroll
    for (int dt = 0; dt < 8; dt++) O[dt] = (f32x4){0.f, 0.f, 0.f, 0.f};
    float l_part[4] = {0.f, 0.f, 0.f, 0.f};
    __syncthreads();                           // Q staged (drains vmcnt)

    for (int kt = 0; kt <= qtile; kt++) {
        if (kt) __syncthreads();               // prior QK/PV reads done
        const ushort* kg = k_t + ((size_t)bh * 1024 + kt * 64) * 128;
        #pragma unroll
        for (int i = 0; i < 4; i++) {
            int idx = i * 256 + tid, row = idx >> 4, cp = idx & 15;
            gll16(kg + row * 128 + (cp ^ (row & 7)) * 8, Ks + idx * 8);
        }
        const ushort* vg = v_t + (size_t)bh * 128 * 1024 + kt * 64;
        #pragma unroll
        for (int i = 0; i < 4; i++) {
            int idx = i * 256 + tid, d = idx >> 3, cp = idx & 7;
            gll16(vg + (size_t)d * 1024 + (cp ^ (d & 7)) * 8, Vs + idx * 8);
        }
        __syncthreads();                       // staging visible

        // S = Q K^T  (scale pre-folded into Q)
        f32x4 sa[4];
        #pragma unroll
        for (int nt = 0; nt < 4; nt++) sa[nt] = (f32x4){0.f, 0.f, 0.f, 0.f};
        #pragma unroll
        for (int c = 0; c < 4; c++) {
            half8 a = *(const half8*)(Qs + (w * 16 + l15) * 128 + ((c * 4 + quad) ^ swz) * 8);
            #pragma unroll
            for (int nt = 0; nt < 4; nt++) {
                half8 kb = *(const half8*)(Ks + (nt * 16 + l15) * 128 + ((c * 4 + quad) ^ swz) * 8);
                sa[nt] = __builtin_amdgcn_mfma_f32_16x16x32_f16(a, kb, sa[nt], 0, 0, 0);
            }
        }

        // fixed-ref softmax: p = exp(s - 4); accumulate per-lane row sums
        const int rowg = qtile * 64 + w * 16 + quad * 4;
        const bool diag = (kt == qtile);
        #pragma unroll
        for (int nt = 0; nt < 4; nt++) {
            int colg = kt * 64 + nt * 16 + l15;
            #pragma unroll
            for (int r = 0; r < 4; r++) {
                float s = sa[nt][r];
                if (diag && colg > rowg + r) s = -1e30f;
                float p = __expf(s - 4.0f);
                l_part[r] += p;
                int prow = quad * 4 + r;
                int clog = nt * 2 + (l15 >> 3);
                Ps[w * 1024 + prow * 64 + (clog ^ (prow & 7)) * 8 + (l15 & 7)] = f2h(p);
            }
        }
        // Ps is wave-private: DS ops per-wave are in-order; stop compiler
        // reordering + wait for the writes, no s_barrier needed.
        asm volatile("s_waitcnt lgkmcnt(0)" ::: "memory");

        // O += P V   (P in A-layout via swizzled LDS; V rows = output dim d)
        half8 pa[2];
        #pragma unroll
        for (int c2 = 0; c2 < 2; c2++)
            pa[c2] = *(const half8*)(Ps + w * 1024 + l15 * 64 + ((c2 * 4 + quad) ^ swz) * 8);
        #pragma unroll
        for (int dt = 0; dt < 8; dt++)
            #pragma unroll
            for (int c2 = 0; c2 < 2; c2++) {
                half8 vb = *(const half8*)(Vs + (dt * 16 + l15) * 64 + ((c2 * 4 + quad) ^ swz) * 8);
                O[dt] = __builtin_amdgcn_mfma_f32_16x16x32_f16(pa[c2], vb, O[dt], 0, 0, 0);
            }
    }

    // reduce l across the 16 lanes sharing each row group, normalize, store
    #pragma unroll
    for (int r = 0; r < 4; r++) {
        float l = l_part[r];
        l += __shfl_xor(l, 1); l += __shfl_xor(l, 2);
        l += __shfl_xor(l, 4); l += __shfl_xor(l, 8);
        l_part[r] = 1.f / l;
    }
    #pragma unroll
    for (int dt = 0; dt < 8; dt++)
        #pragma unroll
        for (int r = 0; r < 4; r++) {
            int srow = qtile * 64 + w * 16 + quad * 4 + r;
            attn[(size_t)((b << 10) + srow) * HID + h * 128 + dt * 16 + l15] =
                f2h(O[dt][r] * l_part[r]);
        }
}

// ---------------------------------------------------------------------------
extern "C" void kernel_launch(void* const* d_in, const int* in_sizes, int n_in,
                              void* d_out, int out_size, void* d_ws, size_t ws_size,
                              hipStream_t stream) {
    const int*   positions = (const int*)d_in[0];
    const float* hidden    = (const float*)d_in[1];
    const float* w_qkv     = (const float*)d_in[2];
    const float* w_dense   = (const float*)d_in[3];
    const float* lora_in   = (const float*)d_in[4];
    const float* lora_out  = (const float*)d_in[5];
    float* out = (float*)d_out;
    char* ws = (char*)d_ws;

    // workspace layout (regions reused over the timeline)
    ushort* hs_f16   = (ushort*)(ws + 0);            // 32 MiB
    ushort* wqkv_f16 = (ushort*)(ws + 33554432);     // 96 MiB
    float*  lmid     = (float*) (ws + 134217728);    // 512 KiB
    ushort* qkv_f16  = (ushort*)(ws + 134742016);    // 96 MiB
    ushort* q_t      = (ushort*)(ws + 0);            // reuse hs region
    ushort* k_t      = (ushort*)(ws + 33554432);     // reuse wqkv region
    ushort* v_t      = (ushort*)(ws + 67108864);
    ushort* wd_f16   = (ushort*)(ws + 134742016);    // reuse qkv region (cast AFTER transpose_v!)
    ushort* attn_f16 = (ushort*)(ws + 168296448);

    cast_f16_kernel<<<24576, 256, 0, stream>>>(w_qkv, wqkv_f16, NQKV * HID);
    lora_mid_kernel<<<M_TOT, 256, 0, stream>>>(hidden, lora_in, lmid, hs_f16);
    gemm_bt_kernel<1, 1><<<dim3(NQKV / 256, M_TOT / 256), 512, 0, stream>>>(
        hs_f16, wqkv_f16, qkv_f16, M_TOT, NQKV, HID, lmid, lora_out);
    rope_kernel<<<32768, 256, 0, stream>>>(positions, qkv_f16, q_t, k_t);
    transpose_v_kernel<<<dim3(16, 128), 256, 0, stream>>>(qkv_f16, v_t);
    // wd_f16 aliases qkv_f16: this cast must come after the last qkv reader.
    cast_f16_kernel<<<8192, 256, 0, stream>>>(w_dense, wd_f16, HID * HID);
    flash_kernel<<<dim3(16, 128), 256, 0, stream>>>(q_t, k_t, v_t, attn_f16);
    gemm_bt_kernel<0, 0><<<dim3(HID / 256, M_TOT / 256), 512, 0, stream>>>(
        attn_f16, wd_f16, out, M_TOT, HID, HID, nullptr, nullptr);
}